// Round 1
// baseline (501.782 us; speedup 1.0000x reference)
//
#include <hip/hip_runtime.h>

#define BB 64
#define TT 2048
#define D_ENC 512
#define D_RNN 1024
#define D_ATT 128
#define NF 32
#define KW 31
#define NCHUNK 16
#define TCHUNK 128

__device__ __forceinline__ float fast_tanh(float x) {
    // tanh(x) = 1 - 2/(exp(2x)+1); exact at saturation (exp->0 or inf)
    float e = __expf(2.0f * x);
    return 1.0f - __fdividef(2.0f, e + 1.0f);
}

// ---------------------------------------------------------------------------
// K1: pq[b][a] = dot(hidden[b,:], query_w[a,:])   (B x 128, K=1024)
// grid (B, 32) x 256 threads; one wave per output element.
// ---------------------------------------------------------------------------
__global__ __launch_bounds__(256) void pq_kernel(
    const float* __restrict__ hid, const float* __restrict__ qw,
    float* __restrict__ pq)
{
    int b = blockIdx.x;
    int wave = threadIdx.x >> 6, lane = threadIdx.x & 63;
    int a = blockIdx.y * 4 + wave;
    const float* hrow = hid + (size_t)b * D_RNN;
    const float* qrow = qw + (size_t)a * D_RNN;
    float acc = 0.f;
#pragma unroll
    for (int j = 0; j < 4; ++j) {
        int k = (j * 64 + lane) * 4;
        float4 h = *(const float4*)(hrow + k);
        float4 q = *(const float4*)(qrow + k);
        acc += h.x * q.x + h.y * q.y + h.z * q.z + h.w * q.w;
    }
#pragma unroll
    for (int off = 32; off; off >>= 1) acc += __shfl_xor(acc, off, 64);
    if (lane == 0) pq[b * D_ATT + a] = acc;
}

// ---------------------------------------------------------------------------
// K2: FUSED per (b, 128-t chunk):
//   conv1d(2->NF,k=31) -> dense(NF->128) -> +pq +pm -> tanh -> dot(vw)
//   -> chunk-local softmax stats (m_c, s_c) and p_t = exp(al - m_c)
//   -> unnormalized partial context  pc[b][c][:] = sum_t p_t * mem[b,t,:]
// Flash-style: no global softmax needed here; K3 combines the 16 chunks.
// Removes: softmax kernel, wts round-trips, ctx memset + 524K atomicAdds.
// ---------------------------------------------------------------------------
__global__ __launch_bounds__(256) void fused_kernel(
    const float* __restrict__ pm,          // (B,T,128)
    const float* __restrict__ awcat,       // (B,2,T)
    const unsigned char* __restrict__ mask,// (B,T) bool
    const float* __restrict__ convw,       // (NF,2,KW)
    const float* __restrict__ ldw,         // (D_ATT,NF)
    const float* __restrict__ vw,          // (128)
    const float* __restrict__ pq,          // (B,128)
    const float* __restrict__ mem,         // (B,T,512)
    float* __restrict__ pmat,              // ws (B,T): p_t = exp(al - m_c)
    float* __restrict__ pc,                // ws (B,16,512): partial context
    float* __restrict__ sm,                // ws (B,16): chunk max
    float* __restrict__ ss)                // ws (B,16): chunk expsum
{
    __shared__ float s_aw[2 * 160];
    __shared__ float s_loc[TCHUNK * NF];
    __shared__ float s_al[TCHUNK];
    __shared__ float s_p[TCHUNK];
    __shared__ float s_red[8];
    __shared__ float4 s_pc[128];

    int b = blockIdx.x;
    int c = blockIdx.y;
    int t0 = c * TCHUNK;
    int tid = threadIdx.x;
    int wave = tid >> 6, lane = tid & 63;

    // stage aw_cat window [t0-15, t0+144] with zero pad (strided: 320 > 256)
    for (int i = tid; i < 320; i += 256) {
        int ch = i / 160, j = i % 160;
        int tg = t0 - 15 + j;
        float v = 0.f;
        if (tg >= 0 && tg < TT) v = awcat[((size_t)b * 2 + ch) * TT + tg];
        s_aw[ch * 160 + j] = v;
    }
    __syncthreads();

    // ---- phase 1: conv1d(2->NF, k=31, same). thread: f = tid&31 owns one
    // filter; g = tid>>5 owns 16 t's; sliding 4-t window keeps taps in regs.
    {
        int f = tid & 31, g = tid >> 5;
        float w[2 * KW];
#pragma unroll
        for (int j = 0; j < 2 * KW; ++j) w[j] = convw[f * 2 * KW + j];
#pragma unroll
        for (int p4 = 0; p4 < 4; ++p4) {
            int tb = g * 16 + p4 * 4;
            float a0 = 0.f, a1 = 0.f, a2 = 0.f, a3 = 0.f;
#pragma unroll
            for (int ch = 0; ch < 2; ++ch) {
                float x[34];
#pragma unroll
                for (int j = 0; j < 34; ++j) x[j] = s_aw[ch * 160 + tb + j];
#pragma unroll
                for (int k = 0; k < KW; ++k) {
                    float wk = w[ch * KW + k];
                    a0 += x[k] * wk; a1 += x[k + 1] * wk;
                    a2 += x[k + 2] * wk; a3 += x[k + 3] * wk;
                }
            }
            s_loc[(tb + 0) * NF + f] = a0;
            s_loc[(tb + 1) * NF + f] = a1;
            s_loc[(tb + 2) * NF + f] = a2;
            s_loc[(tb + 3) * NF + f] = a3;
        }
    }
    __syncthreads();

    // ---- phase 2: energies + alignment -> s_al. wave handles 32 t's;
    // lane = a and a+64; loc_dense rows preloaded to registers.
    {
        float pq0 = pq[b * 128 + lane], pq1 = pq[b * 128 + 64 + lane];
        float vw0 = vw[lane], vw1 = vw[64 + lane];
        float4 lA[8], lB[8];
#pragma unroll
        for (int f4 = 0; f4 < 8; ++f4) {
            lA[f4] = *(const float4*)(ldw + lane * NF + f4 * 4);
            lB[f4] = *(const float4*)(ldw + (64 + lane) * NF + f4 * 4);
        }
        const float* pmb = pm + ((size_t)b * TT + t0) * 128;
        for (int i = 0; i < 32; ++i) {
            int t = wave * 32 + i;
            float pm0 = pmb[(size_t)t * 128 + lane];
            float pm1 = pmb[(size_t)t * 128 + 64 + lane];
            float dA = 0.f, dB = 0.f;
#pragma unroll
            for (int f4 = 0; f4 < 8; ++f4) {
                float4 lv = *(const float4*)&s_loc[t * NF + f4 * 4];
                dA += lv.x * lA[f4].x + lv.y * lA[f4].y + lv.z * lA[f4].z + lv.w * lA[f4].w;
                dB += lv.x * lB[f4].x + lv.y * lB[f4].y + lv.z * lB[f4].z + lv.w * lB[f4].w;
            }
            float eA = fast_tanh(pq0 + pm0 + dA);
            float eB = fast_tanh(pq1 + pm1 + dB);
            float al = vw0 * eA + vw1 * eB;
#pragma unroll
            for (int off = 32; off; off >>= 1) al += __shfl_xor(al, off, 64);
            if (lane == 0) {
                bool mk = mask[(size_t)b * TT + t0 + t] != 0;
                s_al[t] = mk ? -__builtin_inff() : al;
            }
        }
    }
    __syncthreads();

    // ---- phase 3: chunk-local softmax stats.
    float val = (tid < TCHUNK) ? s_al[tid] : -__builtin_inff();
    float mx = val;
#pragma unroll
    for (int off = 32; off; off >>= 1) mx = fmaxf(mx, __shfl_xor(mx, off, 64));
    if (lane == 0) s_red[wave] = mx;
    __syncthreads();
    float M = fmaxf(fmaxf(s_red[0], s_red[1]), fmaxf(s_red[2], s_red[3]));
    // guard: fully-masked chunk (M = -inf) -> p = 0, avoids exp(nan)
    float p = (tid < TCHUNK && M > -__builtin_inff()) ? __expf(val - M) : 0.f;
    float sum = p;
#pragma unroll
    for (int off = 32; off; off >>= 1) sum += __shfl_xor(sum, off, 64);
    if (lane == 0) s_red[4 + wave] = sum;     // disjoint slots, no barrier needed
    if (tid < TCHUNK) s_p[tid] = p;
    __syncthreads();
    if (tid < TCHUNK) pmat[(size_t)b * TT + t0 + tid] = p;
    if (tid == 0) {
        sm[b * NCHUNK + c] = M;
        ss[b * NCHUNK + c] = s_red[4] + s_red[5] + s_red[6] + s_red[7];
    }

    // ---- phase 4: unnormalized partial context over this chunk's 128 t's.
    // Streams 256KB of `memory`; weights are broadcast LDS reads.
    {
        int d4 = tid & 127, th = tid >> 7;
        const float4* mrow = (const float4*)(mem + ((size_t)b * TT + t0) * D_ENC);
        float4 acc = {0.f, 0.f, 0.f, 0.f};
        for (int i = th; i < TCHUNK; i += 2) {
            float w = s_p[i];
            float4 m4 = mrow[(size_t)i * 128 + d4];
            acc.x += w * m4.x; acc.y += w * m4.y;
            acc.z += w * m4.z; acc.w += w * m4.w;
        }
        if (th == 1) s_pc[d4] = acc;
        __syncthreads();
        if (th == 0) {
            float4 o = s_pc[d4];
            float4 r = {acc.x + o.x, acc.y + o.y, acc.z + o.z, acc.w + o.w};
            ((float4*)(pc + ((size_t)b * NCHUNK + c) * D_ENC))[d4] = r;
        }
    }
}

// ---------------------------------------------------------------------------
// K3: combine 16 chunks per batch row: global max M, Z = sum s_c e^{m_c-M};
// ctx[b] = sum_c pc[b][c] * e^{m_c-M} / Z;  wts[b][t] = p_t * e^{m_c-M} / Z.
// ---------------------------------------------------------------------------
__global__ __launch_bounds__(256) void combine_kernel(
    const float* __restrict__ pmat, const float* __restrict__ pc,
    const float* __restrict__ sm, const float* __restrict__ ss,
    float* __restrict__ ctx, float* __restrict__ wts)
{
    int b = blockIdx.x, tid = threadIdx.x;
    __shared__ float s_f[NCHUNK];
    if (tid < 64) {
        float m = (tid < NCHUNK) ? sm[b * NCHUNK + tid] : -__builtin_inff();
        float M = m;
#pragma unroll
        for (int off = 32; off; off >>= 1) M = fmaxf(M, __shfl_xor(M, off, 64));
        float e = (tid < NCHUNK) ? __expf(m - M) : 0.f;
        float z = (tid < NCHUNK) ? ss[b * NCHUNK + tid] * e : 0.f;
        float Z = z;
#pragma unroll
        for (int off = 32; off; off >>= 1) Z += __shfl_xor(Z, off, 64);
        if (tid < NCHUNK) s_f[tid] = e * __fdividef(1.f, Z);
    }
    __syncthreads();
    // context: 512 floats = 256 x float2
    float2 acc = {0.f, 0.f};
    const float2* pcb = (const float2*)(pc + (size_t)b * NCHUNK * D_ENC);
#pragma unroll
    for (int c2 = 0; c2 < NCHUNK; ++c2) {
        float2 v = pcb[(size_t)c2 * 256 + tid];
        float f = s_f[c2];
        acc.x += v.x * f; acc.y += v.y * f;
    }
    ((float2*)(ctx + (size_t)b * D_ENC))[tid] = acc;
    // weights
#pragma unroll
    for (int i = 0; i < 8; ++i) {
        int t = tid + i * 256;
        wts[(size_t)b * TT + t] = pmat[(size_t)b * TT + t] * s_f[t >> 7];
    }
}

extern "C" void kernel_launch(void* const* d_in, const int* in_sizes, int n_in,
                              void* d_out, int out_size, void* d_ws, size_t ws_size,
                              hipStream_t stream)
{
    const float* hid  = (const float*)d_in[0];
    const float* mem  = (const float*)d_in[1];
    const float* pm   = (const float*)d_in[2];
    const float* aw   = (const float*)d_in[3];
    const unsigned char* mask = (const unsigned char*)d_in[4];
    const float* qw   = (const float*)d_in[5];
    const float* vw   = (const float*)d_in[6];
    const float* cw   = (const float*)d_in[7];
    const float* ldw  = (const float*)d_in[8];

    float* out = (float*)d_out;
    float* ctx = out;                          // (B, D_ENC) first in tuple
    float* wts = out + BB * D_ENC;             // (B, T) second

    float* ws   = (float*)d_ws;
    float* pq   = ws;                          // (B,128)      8K floats
    float* pmat = pq + BB * D_ATT;             // (B,T)        128K floats
    float* pc   = pmat + (size_t)BB * TT;      // (B,16,512)   512K floats
    float* sm   = pc + (size_t)BB * NCHUNK * D_ENC;  // (B,16)
    float* ss   = sm + BB * NCHUNK;                  // (B,16)

    pq_kernel<<<dim3(BB, 32), 256, 0, stream>>>(hid, qw, pq);
    fused_kernel<<<dim3(BB, NCHUNK), 256, 0, stream>>>(
        pm, aw, mask, cw, ldw, vw, pq, mem, pmat, pc, sm, ss);
    combine_kernel<<<BB, 256, 0, stream>>>(pmat, pc, sm, ss, ctx, wts);
}

// Round 3
// 461.291 us; speedup vs baseline: 1.0878x; 1.0878x over previous
//
#include <hip/hip_runtime.h>

#define BB 64
#define TT 2048
#define D_ENC 512
#define D_RNN 1024
#define D_ATT 128
#define NF 32
#define KW 31
#define NCHUNK 32
#define TCHUNK 64
#define SAW 96   // staged aw window: 15 + 64 + 15 = 94, padded

__device__ __forceinline__ float fast_tanh(float x) {
    // tanh(x) = 1 - 2/(exp(2x)+1); exact at saturation (exp->0 or inf)
    float e = __expf(2.0f * x);
    return 1.0f - __fdividef(2.0f, e + 1.0f);
}

// ---------------------------------------------------------------------------
// K1: pq[b][a] = dot(hidden[b,:], query_w[a,:])   (B x 128, K=1024)
// grid (B, 32) x 256 threads; one wave per output element.
// ---------------------------------------------------------------------------
__global__ __launch_bounds__(256) void pq_kernel(
    const float* __restrict__ hid, const float* __restrict__ qw,
    float* __restrict__ pq)
{
    int b = blockIdx.x;
    int wave = threadIdx.x >> 6, lane = threadIdx.x & 63;
    int a = blockIdx.y * 4 + wave;
    const float* hrow = hid + (size_t)b * D_RNN;
    const float* qrow = qw + (size_t)a * D_RNN;
    float acc = 0.f;
#pragma unroll
    for (int j = 0; j < 4; ++j) {
        int k = (j * 64 + lane) * 4;
        float4 h = *(const float4*)(hrow + k);
        float4 q = *(const float4*)(qrow + k);
        acc += h.x * q.x + h.y * q.y + h.z * q.z + h.w * q.w;
    }
#pragma unroll
    for (int off = 32; off; off >>= 1) acc += __shfl_xor(acc, off, 64);
    if (lane == 0) pq[b * D_ATT + a] = acc;
}

// ---------------------------------------------------------------------------
// K2: FUSED per (b, 64-t chunk):  conv -> dense -> +pq+pm -> tanh -> dot(vw)
//     -> chunk softmax stats -> unnormalized partial context.
// TCHUNK=64: grid (64,32)=2048 blocks, LDS ~11.5KB -> 8 blocks/CU resident
// (32 waves/CU). Blocks in different phases overlap: some stream `mem`
// while others do conv/energies -> HBM pipe stays fed (R1 was 4 blocks/CU,
// 790 GB/s, occupancy 26%).
// ---------------------------------------------------------------------------
__global__ __launch_bounds__(256) void fused_kernel(
    const float* __restrict__ pm,          // (B,T,128)
    const float* __restrict__ awcat,       // (B,2,T)
    const unsigned char* __restrict__ mask,// (B,T) bool
    const float* __restrict__ convw,       // (NF,2,KW)
    const float* __restrict__ ldw,         // (D_ATT,NF)
    const float* __restrict__ vw,          // (128)
    const float* __restrict__ pq,          // (B,128)
    const float* __restrict__ mem,         // (B,T,512)
    float* __restrict__ pmat,              // ws (B,T): p_t = exp(al - m_c)
    float* __restrict__ pc,                // ws (B,32,512): partial context
    float* __restrict__ sm,                // ws (B,32): chunk max
    float* __restrict__ ss)                // ws (B,32): chunk expsum
{
    __shared__ float s_aw[2 * SAW];
    __shared__ float s_loc[TCHUNK * NF];
    __shared__ float s_al[TCHUNK];
    __shared__ float s_p[TCHUNK];
    __shared__ float4 s_pc[128];

    int b = blockIdx.x;
    int c = blockIdx.y;
    int t0 = c * TCHUNK;
    int tid = threadIdx.x;
    int wave = tid >> 6, lane = tid & 63;

    // stage aw_cat window [t0-15, t0+79] with zero pad (192 entries)
    if (tid < 2 * SAW) {
        int ch = tid / SAW, j = tid % SAW;
        int tg = t0 - 15 + j;
        float v = 0.f;
        if (tg >= 0 && tg < TT) v = awcat[((size_t)b * 2 + ch) * TT + tg];
        s_aw[ch * SAW + j] = v;
    }
    __syncthreads();

    // ---- phase 1: conv1d(2->NF, k=31, same). f = tid&31 owns one filter;
    // g = tid>>5 owns 8 t's; sliding 4-t window keeps taps in registers.
    {
        int f = tid & 31, g = tid >> 5;
        float w[2 * KW];
#pragma unroll
        for (int j = 0; j < 2 * KW; ++j) w[j] = convw[f * 2 * KW + j];
#pragma unroll
        for (int p4 = 0; p4 < 2; ++p4) {
            int tb = g * 8 + p4 * 4;
            float a0 = 0.f, a1 = 0.f, a2 = 0.f, a3 = 0.f;
#pragma unroll
            for (int ch = 0; ch < 2; ++ch) {
                float x[34];
#pragma unroll
                for (int j = 0; j < 34; ++j) x[j] = s_aw[ch * SAW + tb + j];
#pragma unroll
                for (int k = 0; k < KW; ++k) {
                    float wk = w[ch * KW + k];
                    a0 += x[k] * wk; a1 += x[k + 1] * wk;
                    a2 += x[k + 2] * wk; a3 += x[k + 3] * wk;
                }
            }
            s_loc[(tb + 0) * NF + f] = a0;
            s_loc[(tb + 1) * NF + f] = a1;
            s_loc[(tb + 2) * NF + f] = a2;
            s_loc[(tb + 3) * NF + f] = a3;
        }
    }
    __syncthreads();

    // ---- phase 2: energies + alignment -> s_al. wave handles 16 t's;
    // lane owns attention dims a0=2*lane, a1=2*lane+1 (float2 pm loads).
    {
        float2 pqv = ((const float2*)(pq + b * 128))[lane];
        float2 vwv = ((const float2*)vw)[lane];
        float4 lA[8], lB[8];
#pragma unroll
        for (int f4 = 0; f4 < 8; ++f4) {
            lA[f4] = *(const float4*)(ldw + (2 * lane) * NF + f4 * 4);
            lB[f4] = *(const float4*)(ldw + (2 * lane + 1) * NF + f4 * 4);
        }
        const float* pmb = pm + ((size_t)b * TT + t0) * 128;
        for (int i = 0; i < 16; ++i) {
            int t = wave * 16 + i;
            float2 pmv = ((const float2*)(pmb + (size_t)t * 128))[lane];
            float dA = 0.f, dB = 0.f;
#pragma unroll
            for (int f4 = 0; f4 < 8; ++f4) {
                float4 lv = *(const float4*)&s_loc[t * NF + f4 * 4];
                dA += lv.x * lA[f4].x + lv.y * lA[f4].y + lv.z * lA[f4].z + lv.w * lA[f4].w;
                dB += lv.x * lB[f4].x + lv.y * lB[f4].y + lv.z * lB[f4].z + lv.w * lB[f4].w;
            }
            float eA = fast_tanh(pqv.x + pmv.x + dA);
            float eB = fast_tanh(pqv.y + pmv.y + dB);
            float al = vwv.x * eA + vwv.y * eB;
#pragma unroll
            for (int off = 32; off; off >>= 1) al += __shfl_xor(al, off, 64);
            if (lane == 0) {
                bool mk = mask[(size_t)b * TT + t0 + t] != 0;
                s_al[t] = mk ? -__builtin_inff() : al;
            }
        }
    }
    __syncthreads();

    // ---- phase 3: chunk softmax stats, single wave, pure shfl.
    if (wave == 0) {
        float val = s_al[lane];
        float M = val;
#pragma unroll
        for (int off = 32; off; off >>= 1) M = fmaxf(M, __shfl_xor(M, off, 64));
        // guard fully-masked chunk (M = -inf) -> p = 0
        float p = (M > -__builtin_inff()) ? __expf(val - M) : 0.f;
        float sum = p;
#pragma unroll
        for (int off = 32; off; off >>= 1) sum += __shfl_xor(sum, off, 64);
        s_p[lane] = p;
        pmat[(size_t)b * TT + t0 + lane] = p;
        if (lane == 0) { sm[b * NCHUNK + c] = M; ss[b * NCHUNK + c] = sum; }
    }
    __syncthreads();

    // ---- phase 4: unnormalized partial context over 64 t's (128KB stream).
    {
        int d4 = tid & 127, th = tid >> 7;
        const float4* mrow = (const float4*)(mem + ((size_t)b * TT + t0) * D_ENC);
        float4 acc = {0.f, 0.f, 0.f, 0.f};
        for (int i = th; i < TCHUNK; i += 2) {
            float w = s_p[i];
            float4 m4 = mrow[(size_t)i * 128 + d4];
            acc.x += w * m4.x; acc.y += w * m4.y;
            acc.z += w * m4.z; acc.w += w * m4.w;
        }
        if (th == 1) s_pc[d4] = acc;
        __syncthreads();
        if (th == 0) {
            float4 o = s_pc[d4];
            float4 r = {acc.x + o.x, acc.y + o.y, acc.z + o.z, acc.w + o.w};
            ((float4*)(pc + ((size_t)b * NCHUNK + c) * D_ENC))[d4] = r;
        }
    }
}

// ---------------------------------------------------------------------------
// K3: combine 32 chunks per batch row. grid (B,4): block j redundantly
// computes the chunk factors (cheap) then owns ctx[j*128..) and wts t in
// [j*512, j*512+512) -> 256 blocks, no 64-block latency tail.
// ---------------------------------------------------------------------------
__global__ __launch_bounds__(256) void combine_kernel(
    const float* __restrict__ pmat, const float* __restrict__ pc,
    const float* __restrict__ sm, const float* __restrict__ ss,
    float* __restrict__ ctx, float* __restrict__ wts)
{
    int b = blockIdx.x, j = blockIdx.y, tid = threadIdx.x;
    __shared__ float s_f[NCHUNK];
    if (tid < 64) {
        float m = (tid < NCHUNK) ? sm[b * NCHUNK + tid] : -__builtin_inff();
        float M = m;
#pragma unroll
        for (int off = 32; off; off >>= 1) M = fmaxf(M, __shfl_xor(M, off, 64));
        float e = (tid < NCHUNK) ? __expf(m - M) : 0.f;
        float z = (tid < NCHUNK) ? ss[b * NCHUNK + tid] * e : 0.f;
        float Z = z;
#pragma unroll
        for (int off = 32; off; off >>= 1) Z += __shfl_xor(Z, off, 64);
        if (tid < NCHUNK) s_f[tid] = e * __fdividef(1.f, Z);
    }
    __syncthreads();
    // ctx: block j owns d in [j*128, j*128+128)
    if (tid < 128) {
        int d = j * 128 + tid;
        float acc = 0.f;
        const float* pcb = pc + (size_t)b * NCHUNK * D_ENC + d;
#pragma unroll
        for (int cc = 0; cc < NCHUNK; ++cc)
            acc += pcb[(size_t)cc * D_ENC] * s_f[cc];
        ctx[(size_t)b * D_ENC + d] = acc;
    }
    // wts: block j owns t in [j*512, j*512+512)
#pragma unroll
    for (int i = 0; i < 2; ++i) {
        int t = j * 512 + tid + i * 256;
        wts[(size_t)b * TT + t] = pmat[(size_t)b * TT + t] * s_f[t >> 6];
    }
}

extern "C" void kernel_launch(void* const* d_in, const int* in_sizes, int n_in,
                              void* d_out, int out_size, void* d_ws, size_t ws_size,
                              hipStream_t stream)
{
    const float* hid  = (const float*)d_in[0];
    const float* mem  = (const float*)d_in[1];
    const float* pm   = (const float*)d_in[2];
    const float* aw   = (const float*)d_in[3];
    const unsigned char* mask = (const unsigned char*)d_in[4];
    const float* qw   = (const float*)d_in[5];
    const float* vw   = (const float*)d_in[6];
    const float* cw   = (const float*)d_in[7];
    const float* ldw  = (const float*)d_in[8];

    float* out = (float*)d_out;
    float* ctx = out;                          // (B, D_ENC) first in tuple
    float* wts = out + BB * D_ENC;             // (B, T) second

    float* ws   = (float*)d_ws;
    float* pq   = ws;                          // (B,128)
    float* pmat = pq + BB * D_ATT;             // (B,T)
    float* pc   = pmat + (size_t)BB * TT;      // (B,32,512)
    float* sm   = pc + (size_t)BB * NCHUNK * D_ENC;  // (B,32)
    float* ss   = sm + BB * NCHUNK;                  // (B,32)

    pq_kernel<<<dim3(BB, 32), 256, 0, stream>>>(hid, qw, pq);
    fused_kernel<<<dim3(BB, NCHUNK), 256, 0, stream>>>(
        pm, aw, mask, cw, ldw, vw, pq, mem, pmat, pc, sm, ss);
    combine_kernel<<<dim3(BB, 4), 256, 0, stream>>>(pmat, pc, sm, ss, ctx, wts);
}